// Round 2
// baseline (444.331 us; speedup 1.0000x reference)
//
#include <hip/hip_runtime.h>

// newIF forward: T=8 IF-neuron scan + compensated per-neuron threshold.
// Branchless, zero private arrays (everything in named registers), float4
// nontemporal streaming. One thread = 4 contiguous neurons across all 8 steps.
//
// Numerics match the reference bitwise: thre=8.0, (mem - thre >= 0) == (mem >= thre)
// in fp32, post-spike subtraction is the same op, division is IEEE fp32.

typedef float f4 __attribute__((ext_vector_type(4)));

__global__ __launch_bounds__(256) void newif_kernel(
    const f4* __restrict__ x, const float* __restrict__ thresh,
    f4* __restrict__ out, int n4)
{
    int i = blockIdx.x * blockDim.x + threadIdx.x;
    if (i >= n4) return;

    const float thre = thresh[0];
    const float half_thre = 0.5f * thre;

    const f4* xp = x + i;
    f4* op = out + i;

    // 8 independent loads into NAMED registers (no scratch-able array).
    f4 x0 = __builtin_nontemporal_load(xp + 0 * n4);
    f4 x1 = __builtin_nontemporal_load(xp + 1 * n4);
    f4 x2 = __builtin_nontemporal_load(xp + 2 * n4);
    f4 x3 = __builtin_nontemporal_load(xp + 3 * n4);
    f4 x4 = __builtin_nontemporal_load(xp + 4 * n4);
    f4 x5 = __builtin_nontemporal_load(xp + 5 * n4);
    f4 x6 = __builtin_nontemporal_load(xp + 6 * n4);
    f4 x7 = __builtin_nontemporal_load(xp + 7 * n4);

    float m0 = half_thre, m1 = half_thre, m2 = half_thre, m3 = half_thre;
    float c0 = 0.f, c1 = 0.f, c2 = 0.f, c3 = 0.f;

    // Branchless step: select 0/1, fused mem update, reuse xv as spike storage.
#define STEP(xv)                                        \
    {                                                   \
        m0 += xv.x; m1 += xv.y; m2 += xv.z; m3 += xv.w; \
        float s0 = (m0 >= thre) ? 1.0f : 0.0f;          \
        float s1 = (m1 >= thre) ? 1.0f : 0.0f;          \
        float s2 = (m2 >= thre) ? 1.0f : 0.0f;          \
        float s3 = (m3 >= thre) ? 1.0f : 0.0f;          \
        m0 -= s0 * thre; c0 += s0;                      \
        m1 -= s1 * thre; c1 += s1;                      \
        m2 -= s2 * thre; c2 += s2;                      \
        m3 -= s3 * thre; c3 += s3;                      \
        xv.x = s0; xv.y = s1; xv.z = s2; xv.w = s3;     \
    }

    STEP(x0) STEP(x1) STEP(x2) STEP(x3)
    STEP(x4) STEP(x5) STEP(x6) STEP(x7)
#undef STEP

    const float tmax = 8.0f * thre;
#define NEWTHRE(mc, cc)                                                   \
    [&]() -> float {                                                      \
        float compen_value = fminf((mc - half_thre) + cc * thre, tmax);   \
        bool cond = (compen_value > 0.0f) && (cc > 0.0f);                 \
        return cond ? (compen_value / cc) : 0.0f;                         \
    }()
    float n0 = NEWTHRE(m0, c0);
    float n1 = NEWTHRE(m1, c1);
    float n2 = NEWTHRE(m2, c2);
    float n3 = NEWTHRE(m3, c3);
#undef NEWTHRE

    f4 nt = {n0, n1, n2, n3};

    __builtin_nontemporal_store(x0 * nt, op + 0 * n4);
    __builtin_nontemporal_store(x1 * nt, op + 1 * n4);
    __builtin_nontemporal_store(x2 * nt, op + 2 * n4);
    __builtin_nontemporal_store(x3 * nt, op + 3 * n4);
    __builtin_nontemporal_store(x4 * nt, op + 4 * n4);
    __builtin_nontemporal_store(x5 * nt, op + 5 * n4);
    __builtin_nontemporal_store(x6 * nt, op + 6 * n4);
    __builtin_nontemporal_store(x7 * nt, op + 7 * n4);
}

extern "C" void kernel_launch(void* const* d_in, const int* in_sizes, int n_in,
                              void* d_out, int out_size, void* d_ws, size_t ws_size,
                              hipStream_t stream) {
    const float* x      = (const float*)d_in[0];
    const float* thresh = (const float*)d_in[1];
    float* out          = (float*)d_out;

    int n_total = in_sizes[0];          // T*B*C*H*W = 67,108,864
    int n4      = n_total / 8 / 4;      // float4 columns per timestep = 2,097,152

    const int block = 256;
    int grid = (n4 + block - 1) / block;  // 8192 blocks
    newif_kernel<<<grid, block, 0, stream>>>(
        (const f4*)x, thresh, (f4*)out, n4);
}